// Round 17
// baseline (6812.263 us; speedup 1.0000x reference)
//
#include <hip/hip_runtime.h>

typedef unsigned long long u64;
typedef float v2f __attribute__((ext_vector_type(2)));

#define FPS_N   8192
#define FPS_T   256
#define FPS_W   (FPS_T / 64)    // 4 waves, 1 per SIMD
#define FPS_PPT (FPS_N / FPS_T) // 32 points per thread per batch
#define FPS_PR  (FPS_PPT / 2)   // 16 packed pairs per thread per batch

// Packed fp32 ops (VOP3P): two independent IEEE-RN f32 ops per instruction.
// asm-opaque -> no contraction/reassociation. Sub as a + (-c): bit-exact.
__device__ __forceinline__ v2f pk_add(v2f a, v2f b) {
    v2f r; asm("v_pk_add_f32 %0, %1, %2" : "=v"(r) : "v"(a), "v"(b)); return r;
}
__device__ __forceinline__ v2f pk_mul(v2f a, v2f b) {
    v2f r; asm("v_pk_mul_f32 %0, %1, %2" : "=v"(r) : "v"(a), "v"(b)); return r;
}
__device__ __forceinline__ v2f pk_fma(v2f a, v2f b, v2f c) {
    v2f r; asm("v_pk_fma_f32 %0, %1, %2, %3" : "=v"(r) : "v"(a), "v"(b), "v"(c)); return r;
}

// DPP max step; bound_ctrl=true -> OOB reads 0.0f (all values >= 0).
template<int CTRL>
__device__ __forceinline__ float dpp_max_step(float x) {
    int s = __builtin_amdgcn_update_dpp(0, __float_as_int(x), CTRL, 0xf, 0xf, true);
    return fmaxf(x, __int_as_float(s));
}
// Full wave64 max on the VALU pipe; broadcast from lane 63.
__device__ __forceinline__ float wave_max_nn(float x) {
    x = dpp_max_step<0x111>(x);  // row_shr:1
    x = dpp_max_step<0x112>(x);  // row_shr:2
    x = dpp_max_step<0x114>(x);  // row_shr:4
    x = dpp_max_step<0x118>(x);  // row_shr:8
    x = dpp_max_step<0x142>(x);  // row_bcast:15
    x = dpp_max_step<0x143>(x);  // row_bcast:31
    return __int_as_float(__builtin_amdgcn_readlane(__float_as_int(x), 63));
}
__device__ __forceinline__ float readlane_f(float x, int l) {
    return __int_as_float(__builtin_amdgcn_readlane(__float_as_int(x), l));
}

// TWO batches per block, interleaved in one instruction stream: batch B's
// issue fills batch A's serial-latency stalls (reduce, mailbox poll, coord
// fetch) and vice versa. In-order wave => overlap is structural, not
// scheduler luck. No LDS coord tables (can't fit 2x96KB): winner coords are
// fetched from global by UNIFORM index (far is an SGPR after readlane ->
// scalar load, L2-resident, covered by the other batch's work).
// Cross-wave sync: R11's proven relaxed LDS mailbox, one self-tagged u64
// per wave per batch: [63:32]=dist_bits | [25:13]=idx | [12:0]=seq(s+1);
// parity double-buffered => race-free with no fences.
// Distance math is the frozen XLA chain (bit-exact, validated R5..R16):
//   d = fma(dz,dz, fma(dy,dy, dx*dx))
// Ties: descending pair scan (x before y), ballot+ctz per wave, smallest
// slot per block (slot order == ascending point ranges) ==> exact numpy
// argmax first-occurrence semantics. Selection logic identical to R11.
__global__ __launch_bounds__(FPS_T, 1) void fps_kernel(
    const float* __restrict__ coords,
    const int*   __restrict__ init_idx,
    int*         __restrict__ out_idx,
    int M)
{
    __shared__ u64 mbox[2][2][FPS_W];   // [batch][parity][slot]

    const int blk  = blockIdx.x;
    const int bA   = blk * 2, bB = blk * 2 + 1;
    const int tid  = threadIdx.x;
    const int lane = tid & 63;
    const int wv   = tid >> 6;
    const float* cbA = coords + (size_t)bA * FPS_N * 3;
    const float* cbB = coords + (size_t)bB * FPS_N * 3;
    const int base = tid * FPS_PPT;

    if (tid < 16) ((u64*)mbox)[tid] = 0ull;   // no garbage tags

    // ---- stage batch A points into registers (24 float4, coalesced) ----
    v2f pxA[FPS_PR], pyA[FPS_PR], pzA[FPS_PR], dAv[FPS_PR];
    {
        float f[96];
        const float4* c4 = reinterpret_cast<const float4*>(cbA);
        #pragma unroll
        for (int i = 0; i < 24; ++i) {
            float4 v = c4[tid * 24 + i];
            f[i*4+0] = v.x; f[i*4+1] = v.y; f[i*4+2] = v.z; f[i*4+3] = v.w;
        }
        #pragma unroll
        for (int j = 0; j < FPS_PR; ++j) {
            pxA[j] = v2f{f[6*j+0], f[6*j+3]};
            pyA[j] = v2f{f[6*j+1], f[6*j+4]};
            pzA[j] = v2f{f[6*j+2], f[6*j+5]};
            dAv[j] = v2f{1e8f, 1e8f};
        }
    }
    // ---- stage batch B points ----
    v2f pxB[FPS_PR], pyB[FPS_PR], pzB[FPS_PR], dBv[FPS_PR];
    {
        float f[96];
        const float4* c4 = reinterpret_cast<const float4*>(cbB);
        #pragma unroll
        for (int i = 0; i < 24; ++i) {
            float4 v = c4[tid * 24 + i];
            f[i*4+0] = v.x; f[i*4+1] = v.y; f[i*4+2] = v.z; f[i*4+3] = v.w;
        }
        #pragma unroll
        for (int j = 0; j < FPS_PR; ++j) {
            pxB[j] = v2f{f[6*j+0], f[6*j+3]};
            pyB[j] = v2f{f[6*j+1], f[6*j+4]};
            pzB[j] = v2f{f[6*j+2], f[6*j+5]};
            dBv[j] = v2f{1e8f, 1e8f};
        }
    }
    __syncthreads();   // mailbox init visible; only barrier in the kernel

    int farA = init_idx[bA], farB = init_idx[bB];
    // initial centroid coords: uniform index -> scalar L2 loads
    float cxA = cbA[farA*3+0], cyA = cbA[farA*3+1], czA = cbA[farA*3+2];
    float cxB = cbB[farB*3+0], cyB = cbB[farB*3+1], czB = cbB[farB*3+2];

    int bufA[16], bufB[16];   // statically-indexed: stays in VGPRs
    #pragma unroll
    for (int i = 0; i < 16; ++i) { bufA[i] = 0; bufB[i] = 0; }

    for (int so = 0; so < M; so += 16) {
        const int owner = so >> 4;
        #pragma unroll
        for (int si = 0; si < 16; ++si) {
            const int s = so + si;
            if (tid == owner) { bufA[si] = farA; bufB[si] = farB; }

            // ---------- dist A (frozen math) ----------
            const v2f ncxA = v2f{-cxA, -cxA};
            const v2f ncyA = v2f{-cyA, -cyA};
            const v2f nczA = v2f{-czA, -czA};
            float mA = 0.0f;
            #pragma unroll
            for (int j = 0; j < FPS_PR; ++j) {
                v2f dx2 = pk_add(pxA[j], ncxA);
                v2f dy2 = pk_add(pyA[j], ncyA);
                v2f dz2 = pk_add(pzA[j], nczA);
                v2f d2  = pk_fma(dz2, dz2, pk_fma(dy2, dy2, pk_mul(dx2, dx2)));
                v2f nd;
                nd.x = fminf(dAv[j].x, d2.x);
                nd.y = fminf(dAv[j].y, d2.y);
                dAv[j] = nd;
                mA = fmaxf(mA, fmaxf(nd.x, nd.y));
            }
            // ---------- dist B ----------
            const v2f ncxB = v2f{-cxB, -cxB};
            const v2f ncyB = v2f{-cyB, -cyB};
            const v2f nczB = v2f{-czB, -czB};
            float mB = 0.0f;
            #pragma unroll
            for (int j = 0; j < FPS_PR; ++j) {
                v2f dx2 = pk_add(pxB[j], ncxB);
                v2f dy2 = pk_add(pyB[j], ncyB);
                v2f dz2 = pk_add(pzB[j], nczB);
                v2f d2  = pk_fma(dz2, dz2, pk_fma(dy2, dy2, pk_mul(dx2, dx2)));
                v2f nd;
                nd.x = fminf(dBv[j].x, d2.x);
                nd.y = fminf(dBv[j].y, d2.y);
                dBv[j] = nd;
                mB = fmaxf(mB, fmaxf(nd.x, nd.y));
            }

            // ---------- argmax scans (descending, first-occurrence) ----------
            int myidxA = base;
            #pragma unroll
            for (int j = FPS_PR - 1; j >= 0; --j) {
                myidxA = (dAv[j].y == mA) ? base + 2*j + 1 : myidxA;
                myidxA = (dAv[j].x == mA) ? base + 2*j     : myidxA;
            }
            int myidxB = base;
            #pragma unroll
            for (int j = FPS_PR - 1; j >= 0; --j) {
                myidxB = (dBv[j].y == mB) ? base + 2*j + 1 : myidxB;
                myidxB = (dBv[j].x == mB) ? base + 2*j     : myidxB;
            }

            // ---------- stage 1: wave reduces (interleaved chains) ----------
            float wmA = wave_max_nn(mA);
            float wmB = wave_max_nn(mB);
            u64 ballA = __ballot(mA == wmA);
            u64 ballB = __ballot(mB == wmB);
            int flA = (int)__builtin_ctzll(ballA);
            int flB = (int)__builtin_ctzll(ballB);
            int widxA = __builtin_amdgcn_readlane(myidxA, flA);
            int widxB = __builtin_amdgcn_readlane(myidxB, flB);

            // ---------- publish (one tagged u64 per wave per batch) ----------
            const int par = s & 1;
            const unsigned tag = (unsigned)(s + 1);
            if (lane == 0) {
                u64 pkA = ((u64)(unsigned)__float_as_uint(wmA) << 32)
                        | ((u64)(unsigned)widxA << 13) | (u64)tag;
                u64 pkB = ((u64)(unsigned)__float_as_uint(wmB) << 32)
                        | ((u64)(unsigned)widxB << 13) | (u64)tag;
                __hip_atomic_store(&mbox[0][par][wv], pkA,
                                   __ATOMIC_RELAXED, __HIP_MEMORY_SCOPE_WORKGROUP);
                __hip_atomic_store(&mbox[1][par][wv], pkB,
                                   __ATOMIC_RELAXED, __HIP_MEMORY_SCOPE_WORKGROUP);
            }

            // ---------- poll both batches' 4 slots ----------
            const int sl = lane & (FPS_W - 1);
            u64 va, vb;
            do {
                va = __hip_atomic_load(&mbox[0][par][sl],
                                       __ATOMIC_RELAXED, __HIP_MEMORY_SCOPE_WORKGROUP);
                vb = __hip_atomic_load(&mbox[1][par][sl],
                                       __ATOMIC_RELAXED, __HIP_MEMORY_SCOPE_WORKGROUP);
            } while (!__all(((unsigned)(va & 0x1FFFull) == tag) &
                            ((unsigned)(vb & 0x1FFFull) == tag)));

            // ---------- stage 2 A; then uniform coord fetch (L2) ----------
            {
                float cand = __int_as_float((int)(va >> 32));
                int   cidx = (int)((va >> 13) & 0x1FFF);
                float g = cand;
                g = dpp_max_step<0x111>(g);
                g = dpp_max_step<0x112>(g);   // lane 3 = max(slots 0..3)
                float gm = readlane_f(g, 3);
                u64 b2 = __ballot(cand == gm);
                int l2 = (int)__builtin_ctzll(b2);
                farA = __builtin_amdgcn_readlane(cidx, l2);
            }
            cxA = cbA[farA*3+0]; cyA = cbA[farA*3+1]; czA = cbA[farA*3+2];

            // ---------- stage 2 B (covers A's fetch); then B fetch ----------
            {
                float cand = __int_as_float((int)(vb >> 32));
                int   cidx = (int)((vb >> 13) & 0x1FFF);
                float g = cand;
                g = dpp_max_step<0x111>(g);
                g = dpp_max_step<0x112>(g);
                float gm = readlane_f(g, 3);
                u64 b2 = __ballot(cand == gm);
                int l2 = (int)__builtin_ctzll(b2);
                farB = __builtin_amdgcn_readlane(cidx, l2);
            }
            cxB = cbB[farB*3+0]; cyB = cbB[farB*3+1]; czB = cbB[farB*3+2];
            // next iteration's dist A issue covers B's fetch latency
        }
    }

    // Flush recorded indices: thread t wrote iterations [16t, 16t+16).
    int4* obA = reinterpret_cast<int4*>(out_idx + (size_t)bA * M + tid * 16);
    obA[0] = int4{bufA[0],  bufA[1],  bufA[2],  bufA[3]};
    obA[1] = int4{bufA[4],  bufA[5],  bufA[6],  bufA[7]};
    obA[2] = int4{bufA[8],  bufA[9],  bufA[10], bufA[11]};
    obA[3] = int4{bufA[12], bufA[13], bufA[14], bufA[15]};
    int4* obB = reinterpret_cast<int4*>(out_idx + (size_t)bB * M + tid * 16);
    obB[0] = int4{bufB[0],  bufB[1],  bufB[2],  bufB[3]};
    obB[1] = int4{bufB[4],  bufB[5],  bufB[6],  bufB[7]};
    obB[2] = int4{bufB[8],  bufB[9],  bufB[10], bufB[11]};
    obB[3] = int4{bufB[12], bufB[13], bufB[14], bufB[15]};
}

// One 64-thread block per output row: 64 x float4 = 256 floats of values,
// lanes 0-2 copy coords, lane 3 copies mask.
__global__ void gather_kernel(
    const float* __restrict__ coords,
    const float* __restrict__ values,
    const float* __restrict__ mask,
    const int*   __restrict__ idx,
    float* __restrict__ out_coords,
    float* __restrict__ out_values,
    float* __restrict__ out_mask,
    int N, int M, int D)
{
    const int bm = blockIdx.x;
    const int b  = bm / M;
    const int m  = bm - b * M;
    const int j  = idx[bm];
    const int l  = threadIdx.x;

    const float4* src = reinterpret_cast<const float4*>(values + ((size_t)b * N + j) * D);
    float4*       dst = reinterpret_cast<float4*>(out_values + ((size_t)b * M + m) * D);
    dst[l] = src[l];

    if (l < 3) {
        out_coords[((size_t)b * M + m) * 3 + l] = coords[((size_t)b * N + j) * 3 + l];
    } else if (l == 3) {
        out_mask[(size_t)b * M + m] = mask[(size_t)b * N + j];
    }
}

extern "C" void kernel_launch(void* const* d_in, const int* in_sizes, int n_in,
                              void* d_out, int out_size, void* d_ws, size_t ws_size,
                              hipStream_t stream)
{
    const float* coords   = (const float*)d_in[0];
    const float* values   = (const float*)d_in[1];
    const float* mask     = (const float*)d_in[2];
    const int*   init_idx = (const int*)d_in[3];

    const int B = in_sizes[3];
    const int N = in_sizes[2] / B;            // 8192
    const int D = in_sizes[1] / (B * N);      // 256
    const int M = N / 2;                      // SAMPLING_FRACTION = 0.5 -> 4096

    float* out_coords = (float*)d_out;
    float* out_values = out_coords + (size_t)B * M * 3;
    float* out_mask   = out_values + (size_t)B * M * D;

    int* idx = (int*)d_ws;   // B*M ints = 256 KB scratch

    fps_kernel<<<B / 2, FPS_T, 0, stream>>>(coords, init_idx, idx, M);
    gather_kernel<<<B * M, D / 4, 0, stream>>>(coords, values, mask, idx,
                                               out_coords, out_values, out_mask,
                                               N, M, D);
}

// Round 18
// 5691.740 us; speedup vs baseline: 1.1969x; 1.1969x over previous
//
#include <hip/hip_runtime.h>

typedef unsigned long long u64;
typedef float v2f __attribute__((ext_vector_type(2)));

#define FPS_N   8192
#define FPS_T   512             // 8 waves: waves 0-3 batch A, 4-7 batch B
#define FPS_GW  4               // waves per group
#define FPS_GT  256             // threads per group
#define FPS_PPT (FPS_N / FPS_GT) // 32 points per thread
#define FPS_PR  (FPS_PPT / 2)    // 16 packed pairs per thread

// Packed fp32 ops (VOP3P): two independent IEEE-RN f32 ops per instruction.
// asm-opaque -> no contraction/reassociation. Sub as a + (-c): bit-exact.
__device__ __forceinline__ v2f pk_add(v2f a, v2f b) {
    v2f r; asm("v_pk_add_f32 %0, %1, %2" : "=v"(r) : "v"(a), "v"(b)); return r;
}
__device__ __forceinline__ v2f pk_mul(v2f a, v2f b) {
    v2f r; asm("v_pk_mul_f32 %0, %1, %2" : "=v"(r) : "v"(a), "v"(b)); return r;
}
__device__ __forceinline__ v2f pk_fma(v2f a, v2f b, v2f c) {
    v2f r; asm("v_pk_fma_f32 %0, %1, %2, %3" : "=v"(r) : "v"(a), "v"(b), "v"(c)); return r;
}

// DPP max step; bound_ctrl=true -> OOB reads 0.0f (all values >= 0).
template<int CTRL>
__device__ __forceinline__ float dpp_max_step(float x) {
    int s = __builtin_amdgcn_update_dpp(0, __float_as_int(x), CTRL, 0xf, 0xf, true);
    return fmaxf(x, __int_as_float(s));
}
// Full wave64 max on the VALU pipe; broadcast from lane 63.
__device__ __forceinline__ float wave_max_nn(float x) {
    x = dpp_max_step<0x111>(x);  // row_shr:1
    x = dpp_max_step<0x112>(x);  // row_shr:2
    x = dpp_max_step<0x114>(x);  // row_shr:4
    x = dpp_max_step<0x118>(x);  // row_shr:8
    x = dpp_max_step<0x142>(x);  // row_bcast:15
    x = dpp_max_step<0x143>(x);  // row_bcast:31
    return __int_as_float(__builtin_amdgcn_readlane(__float_as_int(x), 63));
}
__device__ __forceinline__ float readlane_f(float x, int l) {
    return __int_as_float(__builtin_amdgcn_readlane(__float_as_int(x), l));
}

// TWO batches per block in SEPARATE WAVE GROUPS (TLP, not ILP): waves 0-3
// run batch A, waves 4-7 batch B -- one A-wave and one B-wave per SIMD.
// When an A-wave stalls (mailbox poll spin, coord-fetch waitcnt) the SIMD
// issues the B-wave's dist loop, and vice versa. Groups never sync with
// each other (independent mailboxes), so their stall patterns interleave --
// unlike R15 (same-batch waves stall together) and R17 (single-wave ILP
// blocked by in-order waitcnt).
// Coords are NOT staged in LDS: winner coords are fetched from global by
// uniform index (R17-verified exact, same f32 bits); LDS holds only the
// two 2-phase mailboxes. Per-group sync = R11's proven relaxed LDS mailbox
// (self-tagged u64, parity double-buffered, no fences).
// Distance math is the frozen XLA chain (bit-exact, validated R5..R17):
//   d = fma(dz,dz, fma(dy,dy, dx*dx))
// Argmax: INCREMENTAL (m,mi) update -- strictly-greater across pairs keeps
// the first max pair; x-preferred (>=) within a pair -- provably identical
// to the verified descending-scan first-occurrence semantics.
__global__ __launch_bounds__(FPS_T) void fps_kernel(
    const float* __restrict__ coords,
    const int*   __restrict__ init_idx,
    int*         __restrict__ out_idx,
    int M)
{
    __shared__ u64 mbox[2][2][FPS_GW];   // [group][parity][slot]

    const int tid   = threadIdx.x;
    const int grp   = tid >> 8;          // 0: batch A, 1: batch B
    const int tg    = tid & (FPS_GT - 1);
    const int lane  = tid & 63;
    const int wvg   = (tid >> 6) & (FPS_GW - 1);   // wave id within group
    const int b     = blockIdx.x * 2 + grp;
    const float* cb = coords + (size_t)b * FPS_N * 3;
    const int base  = tg * FPS_PPT;

    if (tid < 16) ((u64*)mbox)[tid] = 0ull;   // no garbage tags

    // Load own 32 points: 96 contiguous floats = 24 float4 (coalesced)
    float f[96];
    const float4* cb4 = reinterpret_cast<const float4*>(cb);
    #pragma unroll
    for (int i = 0; i < 24; ++i) {
        float4 v = cb4[tg * 24 + i];
        f[i*4+0] = v.x; f[i*4+1] = v.y; f[i*4+2] = v.z; f[i*4+3] = v.w;
    }

    v2f px[FPS_PR], py[FPS_PR], pz[FPS_PR], dist[FPS_PR];
    #pragma unroll
    for (int j = 0; j < FPS_PR; ++j) {
        px[j] = v2f{f[6*j+0], f[6*j+3]};
        py[j] = v2f{f[6*j+1], f[6*j+4]};
        pz[j] = v2f{f[6*j+2], f[6*j+5]};
        dist[j] = v2f{1e8f, 1e8f};   // BIG, matches reference
    }
    __syncthreads();   // mailbox init visible; only barrier in the kernel

    int far = init_idx[b];
    // uniform-index coord fetch (L2; identical bits to the array)
    float cx = cb[far*3+0], cy = cb[far*3+1], cz = cb[far*3+2];

    int buf[16];   // statically-indexed (rule #20): stays in VGPRs
    #pragma unroll
    for (int i = 0; i < 16; ++i) buf[i] = 0;

    for (int so = 0; so < M; so += 16) {
        const int owner = so >> 4;   // thread-in-group owning these 16 iters
        #pragma unroll
        for (int si = 0; si < 16; ++si) {
            const int s = so + si;
            if (tg == owner) buf[si] = far;   // record BEFORE update (reg)

            // --- distance update + incremental argmax (math frozen) ---
            const v2f ncx = v2f{-cx, -cx};   // a + (-c) == a - c, bit-exact
            const v2f ncy = v2f{-cy, -cy};
            const v2f ncz = v2f{-cz, -cz};
            float m = 0.0f;
            int   mi = base;
            #pragma unroll
            for (int j = 0; j < FPS_PR; ++j) {
                v2f dx2 = pk_add(px[j], ncx);
                v2f dy2 = pk_add(py[j], ncy);
                v2f dz2 = pk_add(pz[j], ncz);
                v2f d2  = pk_fma(dz2, dz2, pk_fma(dy2, dy2, pk_mul(dx2, dx2)));
                v2f nd;
                nd.x = fminf(dist[j].x, d2.x);
                nd.y = fminf(dist[j].y, d2.y);
                dist[j] = nd;
                float pmax = fmaxf(nd.x, nd.y);
                int   ex   = (nd.x >= nd.y) ? base + 2*j : base + 2*j + 1;
                bool  upd  = pmax > m;       // strictly > : first pair wins
                m  = upd ? pmax : m;
                mi = upd ? ex   : mi;
            }

            // --- stage 1: wave reduce (VALU pipe) ---
            float wm = wave_max_nn(m);
            u64 ball = __ballot(m == wm);
            int fl   = (int)__builtin_ctzll(ball);
            int widx = __builtin_amdgcn_readlane(mi, fl);

            // --- publish: one relaxed self-tagged u64 LDS write ---
            const int par = s & 1;
            const unsigned tag = (unsigned)(s + 1);
            if (lane == 0) {
                u64 pk = ((u64)(unsigned)__float_as_uint(wm) << 32)
                       | ((u64)(unsigned)widx << 13) | (u64)tag;
                __hip_atomic_store(&mbox[grp][par][wvg], pk,
                                   __ATOMIC_RELAXED, __HIP_MEMORY_SCOPE_WORKGROUP);
            }

            // --- poll own group's 4 slots (lane i -> slot i&3) ---
            u64 v;
            do {
                v = __hip_atomic_load(&mbox[grp][par][lane & (FPS_GW - 1)],
                                      __ATOMIC_RELAXED, __HIP_MEMORY_SCOPE_WORKGROUP);
            } while (!__all((unsigned)(v & 0x1FFFull) == tag));

            // --- stage 2: reduce 4 candidates; uniform coord fetch ---
            float cand = __int_as_float((int)(v >> 32));
            int   cidx = (int)((v >> 13) & 0x1FFF);
            float g = cand;
            g = dpp_max_step<0x111>(g);   // row_shr:1
            g = dpp_max_step<0x112>(g);   // row_shr:2 -> lane 3 = max(s0..s3)
            float gm = readlane_f(g, 3);
            u64 b2 = __ballot(cand == gm);
            int l2 = (int)__builtin_ctzll(b2);  // smallest slot = smallest idx
            far = __builtin_amdgcn_readlane(cidx, l2);
            cx = cb[far*3+0]; cy = cb[far*3+1]; cz = cb[far*3+2];
            // fetch latency is hidden by the OTHER group's waves (TLP)
        }
    }

    // Flush recorded indices: thread tg wrote iterations [16tg, 16tg+16).
    int4* ob = reinterpret_cast<int4*>(out_idx + (size_t)b * M + tg * 16);
    ob[0] = int4{buf[0],  buf[1],  buf[2],  buf[3]};
    ob[1] = int4{buf[4],  buf[5],  buf[6],  buf[7]};
    ob[2] = int4{buf[8],  buf[9],  buf[10], buf[11]};
    ob[3] = int4{buf[12], buf[13], buf[14], buf[15]};
}

// One 64-thread block per output row: 64 x float4 = 256 floats of values,
// lanes 0-2 copy coords, lane 3 copies mask.
__global__ void gather_kernel(
    const float* __restrict__ coords,
    const float* __restrict__ values,
    const float* __restrict__ mask,
    const int*   __restrict__ idx,
    float* __restrict__ out_coords,
    float* __restrict__ out_values,
    float* __restrict__ out_mask,
    int N, int M, int D)
{
    const int bm = blockIdx.x;
    const int b  = bm / M;
    const int m  = bm - b * M;
    const int j  = idx[bm];
    const int l  = threadIdx.x;

    const float4* src = reinterpret_cast<const float4*>(values + ((size_t)b * N + j) * D);
    float4*       dst = reinterpret_cast<float4*>(out_values + ((size_t)b * M + m) * D);
    dst[l] = src[l];

    if (l < 3) {
        out_coords[((size_t)b * M + m) * 3 + l] = coords[((size_t)b * N + j) * 3 + l];
    } else if (l == 3) {
        out_mask[(size_t)b * M + m] = mask[(size_t)b * N + j];
    }
}

extern "C" void kernel_launch(void* const* d_in, const int* in_sizes, int n_in,
                              void* d_out, int out_size, void* d_ws, size_t ws_size,
                              hipStream_t stream)
{
    const float* coords   = (const float*)d_in[0];
    const float* values   = (const float*)d_in[1];
    const float* mask     = (const float*)d_in[2];
    const int*   init_idx = (const int*)d_in[3];

    const int B = in_sizes[3];
    const int N = in_sizes[2] / B;            // 8192
    const int D = in_sizes[1] / (B * N);      // 256
    const int M = N / 2;                      // SAMPLING_FRACTION = 0.5 -> 4096

    float* out_coords = (float*)d_out;
    float* out_values = out_coords + (size_t)B * M * 3;
    float* out_mask   = out_values + (size_t)B * M * D;

    int* idx = (int*)d_ws;   // B*M ints = 256 KB scratch

    fps_kernel<<<B / 2, FPS_T, 0, stream>>>(coords, init_idx, idx, M);
    gather_kernel<<<B * M, D / 4, 0, stream>>>(coords, values, mask, idx,
                                               out_coords, out_values, out_mask,
                                               N, M, D);
}